// Round 6
// baseline (388.227 us; speedup 1.0000x reference)
//
#include <hip/hip_runtime.h>
#include <stdint.h>

#define D_  64
#define DP1 65
#define M_  512
#define N_  4096

typedef float f32x4 __attribute__((ext_vector_type(4)));
typedef _Float16 h8 __attribute__((ext_vector_type(8)));

// ---------------- prep kernels ----------------
__global__ void prep1(const float* __restrict__ A, const float* __restrict__ K0,
                      float* symA, float* sumK2, float* params){
  int t = threadIdx.x;
  for (int idx = t; idx < DP1*DP1; idx += 256){
    int e = idx / DP1, d = idx % DP1;
    float s = 0.f;
    for (int r = 0; r < 10; ++r) s += A[r*DP1+e]*A[r*DP1+d];
    symA[idx] = s;
  }
  for (int m = t; m < M_; m += 256){
    float s = 0.f;
    for (int k = 0; k < D_; ++k){ float v = K0[m*DP1+k]; s += v*v; }
    sumK2[m] = s;
  }
  __syncthreads();
  if (t == 0){
    float tr = 0.f;
    for (int d = 0; d < D_; ++d) tr += symA[d*DP1+d];
    params[0] = tr;
  }
}

// K1 -> f16 row-major + f16 transposed (LDS tile transpose)
__global__ void prep2(const float* __restrict__ K1, _Float16* K1h, _Float16* K1Th){
  __shared__ float tile[64][65];
  int r0 = blockIdx.x*64, c0 = blockIdx.y*64;
  int t = threadIdx.x;
  for (int it = 0; it < 16; ++it){
    int lin = it*256 + t;
    int r = lin >> 6, c = lin & 63;
    float v = K1[(r0+r)*M_ + c0+c];
    tile[r][c] = v;
    K1h[(r0+r)*M_ + c0+c] = (_Float16)v;
  }
  __syncthreads();
  for (int it = 0; it < 16; ++it){
    int lin = it*256 + t;
    int r = lin >> 6, c = lin & 63;
    K1Th[(c0+r)*M_ + (r0+c)] = (_Float16)tile[c][r];
  }
}

// K0T f16, 80 rows x 512 (rows 65..79 zero). Rows 0..63 double as Kopen^T.
__global__ void prep3(const float* __restrict__ K0, _Float16* K0Th){
  int idx = blockIdx.x*256 + threadIdx.x;
  if (idx >= 80*M_) return;
  int d = idx / M_, i = idx % M_;
  float v = (d < DP1) ? K0[i*DP1 + d] : 0.f;
  K0Th[idx] = (_Float16)v;
}

// ---------------- opening + elementwise ----------------
__global__ void openk(const float* __restrict__ x, const float* __restrict__ tptr,
                      const float* __restrict__ K0, const float* __restrict__ b0,
                      _Float16* u0h, _Float16* ah,
                      float* trH0, const float* __restrict__ params){
  __shared__ float sS[64][66];
  __shared__ float sK[64][66];
  int n0 = blockIdx.x*64, m0 = blockIdx.y*64;
  int t = threadIdx.x;
  float tval = tptr[0];
  for (int it = 0; it < 17; ++it){
    int lin = it*256 + t;
    if (lin < 64*65){
      int r = lin/65, c = lin%65;
      sS[r][c] = (c < 64) ? x[(n0+r)*64 + c] : tval;
      sK[r][c] = K0[(m0+r)*DP1 + c];
    }
  }
  __syncthreads();
  int tn = (t>>4)*4, tm = (t&15)*4;
  float acc[4][4] = {};
  for (int e = 0; e < DP1; ++e){
    float sv[4], kv[4];
    for (int i=0;i<4;++i){ sv[i]=sS[tn+i][e]; kv[i]=sK[tm+i][e]; }
    for (int i=0;i<4;++i) for(int j=0;j<4;++j) acc[i][j] += sv[i]*kv[j];
  }
  for (int i=0;i<4;++i) for(int j=0;j<4;++j){
    int n = n0+tn+i, m = m0+tm+j;
    float o = acc[i][j] + b0[m];
    float a = tanhf(o);
    float ax = fabsf(o);
    float u0 = ax + log1pf(expf(-2.f*ax));
    u0h[n*M_+m] = (_Float16)u0;
    ah[n*M_+m]  = (_Float16)a;
  }
  if (m0 == 0 && t < 64) trH0[n0+t] = params[0];
}

// ---------------- 4096x512x512 GEMMs (MODE 0: lin1, MODE 1: z1) ----------------
template<int MODE>
__launch_bounds__(256, 4)
__global__ void gemm512(const _Float16* __restrict__ Ah, const _Float16* __restrict__ Wh,
                        const float* __restrict__ bias, const float* __restrict__ w,
                        const _Float16* __restrict__ ah, const float* __restrict__ sumK2,
                        _Float16* out0, _Float16* out1, float* trH0){
  int n0 = blockIdx.x*64, i0 = blockIdx.y*64;
  int t = threadIdx.x;
  int wv = t>>6, l = t&63;
  int r15 = l & 15;
  int krow = (l>>4)*8;
  const _Float16* abase = Ah + (size_t)(n0 + wv*16 + r15)*M_ + krow;
  const _Float16* wb0 = Wh + (size_t)(i0 +  0 + r15)*M_ + krow;
  const _Float16* wb1 = Wh + (size_t)(i0 + 16 + r15)*M_ + krow;
  const _Float16* wb2 = Wh + (size_t)(i0 + 32 + r15)*M_ + krow;
  const _Float16* wb3 = Wh + (size_t)(i0 + 48 + r15)*M_ + krow;
  f32x4 zero = {0.f,0.f,0.f,0.f};
  f32x4 acc[4]; for (int k=0;k<4;++k) acc[k]=zero;
  h8 af_c = *(const h8*)(abase);
  h8 bf_c0 = *(const h8*)(wb0);
  h8 bf_c1 = *(const h8*)(wb1);
  h8 bf_c2 = *(const h8*)(wb2);
  h8 bf_c3 = *(const h8*)(wb3);
  #pragma unroll
  for (int ii = 0; ii < 16; ++ii){
    const int j0 = ii*32;
    h8 af_n, bf_n0, bf_n1, bf_n2, bf_n3;
    if (ii < 15){
      af_n  = *(const h8*)(abase + j0 + 32);
      bf_n0 = *(const h8*)(wb0 + j0 + 32);
      bf_n1 = *(const h8*)(wb1 + j0 + 32);
      bf_n2 = *(const h8*)(wb2 + j0 + 32);
      bf_n3 = *(const h8*)(wb3 + j0 + 32);
    }
    acc[0] = __builtin_amdgcn_mfma_f32_16x16x32_f16(af_c, bf_c0, acc[0], 0, 0, 0);
    acc[1] = __builtin_amdgcn_mfma_f32_16x16x32_f16(af_c, bf_c1, acc[1], 0, 0, 0);
    acc[2] = __builtin_amdgcn_mfma_f32_16x16x32_f16(af_c, bf_c2, acc[2], 0, 0, 0);
    acc[3] = __builtin_amdgcn_mfma_f32_16x16x32_f16(af_c, bf_c3, acc[3], 0, 0, 0);
    if (ii < 15){
      af_c = af_n; bf_c0 = bf_n0; bf_c1 = bf_n1; bf_c2 = bf_n2; bf_c3 = bf_n3;
    }
  }
  if (MODE == 0){
    for (int kt=0;kt<4;++kt) for (int r=0;r<4;++r){
      int n = n0+wv*16+(l>>4)*4+r;
      int i = i0+kt*16+r15;
      float v = acc[kt][r] + bias[i];
      float tl = tanhf(v);
      out0[n*M_+i] = (_Float16)(tl*w[i]);
      out1[n*M_+i] = (_Float16)((1.f-tl*tl)*w[i]);
    }
  } else {
    for (int r=0;r<4;++r){
      int n = n0+wv*16+(l>>4)*4+r;
      float rowpart = 0.f;
      for (int kt=0;kt<4;++kt){
        int i = i0+kt*16+r15;
        float z1 = acc[kt][r] + w[i];
        float a = (float)ah[n*M_+i];
        out0[n*M_+i] = (_Float16)(a*z1);
        rowpart += (1.f-a*a)*z1*sumK2[i];
      }
      for (int m=1;m<16;m<<=1) rowpart += __shfl_xor(rowpart, m);
      if (r15==0) atomicAdd(&trH0[n], rowpart);
    }
  }
}

// ---------------- z0 = az1 @ K0 (N x 80, K=512) ----------------
__launch_bounds__(256, 4)
__global__ void gemmz0(const _Float16* __restrict__ az1h, const _Float16* __restrict__ K0Th,
                       float* z0){
  int n0 = blockIdx.x*64;
  int t = threadIdx.x, wv = t>>6, l = t&63;
  int r15 = l & 15;
  int krow = (l>>4)*8;
  const _Float16* abase = az1h + (size_t)(n0 + wv*16 + r15)*M_ + krow;
  const _Float16* kb0 = K0Th + (size_t)( 0 + r15)*M_ + krow;
  const _Float16* kb1 = K0Th + (size_t)(16 + r15)*M_ + krow;
  const _Float16* kb2 = K0Th + (size_t)(32 + r15)*M_ + krow;
  const _Float16* kb3 = K0Th + (size_t)(48 + r15)*M_ + krow;
  const _Float16* kb4 = K0Th + (size_t)(64 + r15)*M_ + krow;
  f32x4 zero = {0.f,0.f,0.f,0.f};
  f32x4 acc[5]; for (int k=0;k<5;++k) acc[k]=zero;
  h8 af_c = *(const h8*)(abase);
  h8 b0c = *(const h8*)(kb0);
  h8 b1c = *(const h8*)(kb1);
  h8 b2c = *(const h8*)(kb2);
  h8 b3c = *(const h8*)(kb3);
  h8 b4c = *(const h8*)(kb4);
  #pragma unroll
  for (int ii = 0; ii < 16; ++ii){
    const int j0 = ii*32;
    h8 af_n, b0n, b1n, b2n, b3n, b4n;
    if (ii < 15){
      af_n = *(const h8*)(abase + j0 + 32);
      b0n = *(const h8*)(kb0 + j0 + 32);
      b1n = *(const h8*)(kb1 + j0 + 32);
      b2n = *(const h8*)(kb2 + j0 + 32);
      b3n = *(const h8*)(kb3 + j0 + 32);
      b4n = *(const h8*)(kb4 + j0 + 32);
    }
    acc[0] = __builtin_amdgcn_mfma_f32_16x16x32_f16(af_c, b0c, acc[0], 0, 0, 0);
    acc[1] = __builtin_amdgcn_mfma_f32_16x16x32_f16(af_c, b1c, acc[1], 0, 0, 0);
    acc[2] = __builtin_amdgcn_mfma_f32_16x16x32_f16(af_c, b2c, acc[2], 0, 0, 0);
    acc[3] = __builtin_amdgcn_mfma_f32_16x16x32_f16(af_c, b3c, acc[3], 0, 0, 0);
    acc[4] = __builtin_amdgcn_mfma_f32_16x16x32_f16(af_c, b4c, acc[4], 0, 0, 0);
    if (ii < 15){
      af_c = af_n; b0c = b0n; b1c = b1n; b2c = b2n; b3c = b3n; b4c = b4n;
    }
  }
  for (int dt=0; dt<5; ++dt) for (int r=0;r<4;++r){
    int n = n0+wv*16+(l>>4)*4+r;
    int d = dt*16+r15;
    z0[n*80+d] = acc[dt][r];
  }
}

// ---------------- dominant: t1 partials --------------------------------------------
// Block = 256 thr (4 waves), 3 blocks/CU (LDS 32KB, launch_bounds(256,3) -> ~170 regs).
// Each block: 4 samples x 64 K1 rows (wave: 16 rows) x 32 Kopen cols (k-half kh).
// Ks = Kopen^T k-half in LDS, XOR-swizzled chunks (c ^ (k&15)). a folded into the
// A-operand in registers (packed f16 mul). af/av prefetched 1 step ahead; with the
// 170-reg budget the prefetch actually stays in registers (R5 failure: 64-reg squeeze).
__launch_bounds__(256, 3)
__global__ void kjk5(const _Float16* __restrict__ K1h, const _Float16* __restrict__ K0Th,
                     const _Float16* __restrict__ ah, const _Float16* __restrict__ ch,
                     float* trH0){
  __shared__ _Float16 Ks[32*512];   // 32 KB
  int t = threadIdx.x;
  int n0 = blockIdx.x*4;
  int rg = blockIdx.y;              // 0..7 : 64-row group
  int kh = blockIdx.z;              // 0..1 : 32-col half of Kopen
  int wv = t>>6, l = t&63;
  int k15 = l & 15, g = l>>4;       // g in 0..3
  int rowbase = rg*64 + wv*16;
  const _Float16* k1p  = K1h + (size_t)(rowbase + k15)*M_ + g*8;
  const _Float16* avp0 = ah + (size_t)(n0+0)*M_ + g*8;
  const _Float16* avp1 = ah + (size_t)(n0+1)*M_ + g*8;
  const _Float16* avp2 = ah + (size_t)(n0+2)*M_ + g*8;
  const _Float16* avp3 = ah + (size_t)(n0+3)*M_ + g*8;
  // prologue loads (latency hides under staging)
  h8 af_c = *(const h8*)(k1p);
  h8 av_c0 = *(const h8*)(avp0);
  h8 av_c1 = *(const h8*)(avp1);
  h8 av_c2 = *(const h8*)(avp2);
  h8 av_c3 = *(const h8*)(avp3);
  // stage Ks: rows k = kh*32 .. kh*32+31 of K0Th, chunk c stored at c ^ (k&15)
  #pragma unroll
  for (int it = 0; it < 8; ++it){
    int cc = it*256 + t;            // 2048 chunks: 32 rows x 64 chunks
    int k = cc >> 6, c = cc & 63;
    h8 v = *(const h8*)(K0Th + (size_t)(kh*32 + k)*M_ + c*8);
    *(h8*)(&Ks[k*512 + ((c ^ (k & 15))*8)]) = v;
  }
  __syncthreads();
  f32x4 zero = {0.f,0.f,0.f,0.f};
  f32x4 acc[2][4];                  // [ktile][sample]
  #pragma unroll
  for (int kt=0;kt<2;++kt) for (int s=0;s<4;++s) acc[kt][s]=zero;
  #pragma unroll
  for (int step = 0; step < 16; ++step){
    const int j0 = step*32;
    // kf ds_reads for this step
    int p = ((step*4 + g) ^ k15) * 8;
    h8 kf0 = *(const h8*)(&Ks[(k15     )*512 + p]);
    h8 kf1 = *(const h8*)(&Ks[(16 + k15)*512 + p]);
    // prefetch next step's globals
    h8 af_n, av_n0, av_n1, av_n2, av_n3;
    if (step < 15){
      af_n  = *(const h8*)(k1p  + j0 + 32);
      av_n0 = *(const h8*)(avp0 + j0 + 32);
      av_n1 = *(const h8*)(avp1 + j0 + 32);
      av_n2 = *(const h8*)(avp2 + j0 + 32);
      av_n3 = *(const h8*)(avp3 + j0 + 32);
    }
    {
      h8 ap = af_c*av_c0;
      acc[0][0] = __builtin_amdgcn_mfma_f32_16x16x32_f16(ap, kf0, acc[0][0], 0, 0, 0);
      acc[1][0] = __builtin_amdgcn_mfma_f32_16x16x32_f16(ap, kf1, acc[1][0], 0, 0, 0);
    }
    {
      h8 ap = af_c*av_c1;
      acc[0][1] = __builtin_amdgcn_mfma_f32_16x16x32_f16(ap, kf0, acc[0][1], 0, 0, 0);
      acc[1][1] = __builtin_amdgcn_mfma_f32_16x16x32_f16(ap, kf1, acc[1][1], 0, 0, 0);
    }
    {
      h8 ap = af_c*av_c2;
      acc[0][2] = __builtin_amdgcn_mfma_f32_16x16x32_f16(ap, kf0, acc[0][2], 0, 0, 0);
      acc[1][2] = __builtin_amdgcn_mfma_f32_16x16x32_f16(ap, kf1, acc[1][2], 0, 0, 0);
    }
    {
      h8 ap = af_c*av_c3;
      acc[0][3] = __builtin_amdgcn_mfma_f32_16x16x32_f16(ap, kf0, acc[0][3], 0, 0, 0);
      acc[1][3] = __builtin_amdgcn_mfma_f32_16x16x32_f16(ap, kf1, acc[1][3], 0, 0, 0);
    }
    if (step < 15){
      af_c = af_n; av_c0 = av_n0; av_c1 = av_n1; av_c2 = av_n2; av_c3 = av_n3;
    }
  }
  // epilogue: per lane rows i = rowbase + g*4 + r (both ktiles share i)
  #pragma unroll
  for (int s = 0; s < 4; ++s){
    float part = 0.f;
    #pragma unroll
    for (int r = 0; r < 4; ++r){
      int i = rowbase + g*4 + r;
      float ci = (float)ch[(size_t)(n0+s)*M_ + i];
      float v0 = acc[0][s][r];
      float v1 = acc[1][s][r];
      part += ci*(v0*v0 + v1*v1);
    }
    for (int m=32;m>=1;m>>=1) part += __shfl_xor(part, m);
    if (l == 0) atomicAdd(&trH0[n0+s], part);
  }
}

// ---------------- final: grad, outputs ----------------
__global__ void finalk(const float* __restrict__ x, const float* __restrict__ tptr,
                       const float* __restrict__ symA, const float* __restrict__ c_w,
                       const float* __restrict__ z0, const float* __restrict__ trH0,
                       float* out){
  __shared__ float sA[DP1*DP1];
  int t = threadIdx.x;
  for (int i = t; i < DP1*DP1; i += 256) sA[i] = symA[i];
  __syncthreads();
  int wv = t>>6, l = t&63;
  int n = blockIdx.x*4 + wv;
  float tval = tptr[0];
  float sv = x[n*64 + l];
  float acc = z0[n*80 + l] + c_w[l];
  for (int e = 0; e < 64; ++e){
    float se = __shfl(sv, e);
    acc += se * sA[l*DP1 + e];     // symA symmetric
  }
  acc += tval * sA[l*DP1 + 64];
  // grad[64]
  float g64 = sv * sA[64*DP1 + l];
  for (int m=32;m>=1;m>>=1) g64 += __shfl_xor(g64, m);
  g64 += tval*sA[64*DP1+64] + z0[n*80+64] + c_w[64];
  float dz = -acc;
  out[n*64 + l] = dz;
  float q = dz*dz;
  for (int m=32;m>=1;m>>=1) q += __shfl_xor(q, m);
  float costL = 0.5f*q;
  if (l == 0){
    out[N_*64 + n]        = -trH0[n];
    out[N_*64 + N_ + n]   = costL;
    out[N_*64 + 2*N_ + n] = fabsf(-g64 + costL);
  }
}

extern "C" void kernel_launch(void* const* d_in, const int* in_sizes, int n_in,
                              void* d_out, int out_size, void* d_ws, size_t ws_size,
                              hipStream_t stream){
  const float* x   = (const float*)d_in[0];
  const float* tp  = (const float*)d_in[1];
  const float* K0  = (const float*)d_in[2];
  const float* b0  = (const float*)d_in[3];
  const float* K1  = (const float*)d_in[4];
  const float* b1  = (const float*)d_in[5];
  const float* w   = (const float*)d_in[6];
  const float* A   = (const float*)d_in[7];
  const float* c_w = (const float*)d_in[8];
  float* out = (float*)d_out;

  char* ws = (char*)d_ws;
  size_t off = 0;
  auto alloc = [&](size_t bytes)->void*{
    void* p = ws + off; off += bytes; off = (off + 255) & ~(size_t)255; return p;
  };
  _Float16* K1h   = (_Float16*)alloc(512*512*2);
  _Float16* K1Th  = (_Float16*)alloc(512*512*2);
  _Float16* K0Th  = (_Float16*)alloc(80*512*2);
  float* symA     = (float*)alloc(DP1*DP1*4);
  float* sumK2    = (float*)alloc(512*4);
  float* params   = (float*)alloc(256);
  _Float16* u0h   = (_Float16*)alloc((size_t)N_*M_*2);
  _Float16* ah    = (_Float16*)alloc((size_t)N_*M_*2);
  _Float16* tl1wh = (_Float16*)alloc((size_t)N_*M_*2);
  _Float16* ch    = (_Float16*)alloc((size_t)N_*M_*2);
  _Float16* az1h  = (_Float16*)alloc((size_t)N_*M_*2);
  float* z0       = (float*)alloc((size_t)N_*80*4);
  float* trH0     = (float*)alloc(N_*4);

  prep1<<<1, 256, 0, stream>>>(A, K0, symA, sumK2, params);
  prep2<<<dim3(8,8), 256, 0, stream>>>(K1, K1h, K1Th);
  prep3<<<160, 256, 0, stream>>>(K0, K0Th);
  openk<<<dim3(N_/64, M_/64), 256, 0, stream>>>(x, tp, K0, b0, u0h, ah, trH0, params);
  gemm512<0><<<dim3(N_/64, M_/64), 256, 0, stream>>>(u0h, K1h, b1, w, nullptr, nullptr,
                                                     tl1wh, ch, nullptr);
  gemm512<1><<<dim3(N_/64, M_/64), 256, 0, stream>>>(tl1wh, K1Th, nullptr, w, ah, sumK2,
                                                     az1h, nullptr, trH0);
  gemmz0<<<N_/64, 256, 0, stream>>>(az1h, K0Th, z0);
  kjk5<<<dim3(N_/4, 8, 2), 256, 0, stream>>>(K1h, K0Th, ah, ch, trH0);
  finalk<<<N_/4, 256, 0, stream>>>(x, tp, symA, c_w, z0, trH0, out);
}

// Round 7
// 359.700 us; speedup vs baseline: 1.0793x; 1.0793x over previous
//
#include <hip/hip_runtime.h>
#include <stdint.h>

#define D_  64
#define DP1 65
#define M_  512
#define N_  4096

typedef float f32x4 __attribute__((ext_vector_type(4)));
typedef _Float16 h8 __attribute__((ext_vector_type(8)));

// ---------------- prep kernels ----------------
__global__ void prep1(const float* __restrict__ A, const float* __restrict__ K0,
                      float* symA, float* sumK2, float* params){
  int t = threadIdx.x;
  for (int idx = t; idx < DP1*DP1; idx += 256){
    int e = idx / DP1, d = idx % DP1;
    float s = 0.f;
    for (int r = 0; r < 10; ++r) s += A[r*DP1+e]*A[r*DP1+d];
    symA[idx] = s;
  }
  for (int m = t; m < M_; m += 256){
    float s = 0.f;
    for (int k = 0; k < D_; ++k){ float v = K0[m*DP1+k]; s += v*v; }
    sumK2[m] = s;
  }
  __syncthreads();
  if (t == 0){
    float tr = 0.f;
    for (int d = 0; d < D_; ++d) tr += symA[d*DP1+d];
    params[0] = tr;
  }
}

// K1 -> f16 row-major + f16 transposed (LDS tile transpose)
__global__ void prep2(const float* __restrict__ K1, _Float16* K1h, _Float16* K1Th){
  __shared__ float tile[64][65];
  int r0 = blockIdx.x*64, c0 = blockIdx.y*64;
  int t = threadIdx.x;
  for (int it = 0; it < 16; ++it){
    int lin = it*256 + t;
    int r = lin >> 6, c = lin & 63;
    float v = K1[(r0+r)*M_ + c0+c];
    tile[r][c] = v;
    K1h[(r0+r)*M_ + c0+c] = (_Float16)v;
  }
  __syncthreads();
  for (int it = 0; it < 16; ++it){
    int lin = it*256 + t;
    int r = lin >> 6, c = lin & 63;
    K1Th[(c0+r)*M_ + (r0+c)] = (_Float16)tile[c][r];
  }
}

// K0T f16, 80 rows x 512 (rows 65..79 zero). Rows 0..63 double as Kopen^T.
__global__ void prep3(const float* __restrict__ K0, _Float16* K0Th){
  int idx = blockIdx.x*256 + threadIdx.x;
  if (idx >= 80*M_) return;
  int d = idx / M_, i = idx % M_;
  float v = (d < DP1) ? K0[i*DP1 + d] : 0.f;
  K0Th[idx] = (_Float16)v;
}

// ---------------- opening + elementwise ----------------
__global__ void openk(const float* __restrict__ x, const float* __restrict__ tptr,
                      const float* __restrict__ K0, const float* __restrict__ b0,
                      _Float16* u0h, _Float16* ah,
                      float* trH0, const float* __restrict__ params){
  __shared__ float sS[64][66];
  __shared__ float sK[64][66];
  int n0 = blockIdx.x*64, m0 = blockIdx.y*64;
  int t = threadIdx.x;
  float tval = tptr[0];
  for (int it = 0; it < 17; ++it){
    int lin = it*256 + t;
    if (lin < 64*65){
      int r = lin/65, c = lin%65;
      sS[r][c] = (c < 64) ? x[(n0+r)*64 + c] : tval;
      sK[r][c] = K0[(m0+r)*DP1 + c];
    }
  }
  __syncthreads();
  int tn = (t>>4)*4, tm = (t&15)*4;
  float acc[4][4] = {};
  for (int e = 0; e < DP1; ++e){
    float sv[4], kv[4];
    for (int i=0;i<4;++i){ sv[i]=sS[tn+i][e]; kv[i]=sK[tm+i][e]; }
    for (int i=0;i<4;++i) for(int j=0;j<4;++j) acc[i][j] += sv[i]*kv[j];
  }
  for (int i=0;i<4;++i) for(int j=0;j<4;++j){
    int n = n0+tn+i, m = m0+tm+j;
    float o = acc[i][j] + b0[m];
    float a = tanhf(o);
    float ax = fabsf(o);
    float u0 = ax + log1pf(expf(-2.f*ax));
    u0h[n*M_+m] = (_Float16)u0;
    ah[n*M_+m]  = (_Float16)a;
  }
  if (m0 == 0 && t < 64) trH0[n0+t] = params[0];
}

// ---------------- 4096x512x512 GEMMs (MODE 0: lin1, MODE 1: z1) ----------------
template<int MODE>
__launch_bounds__(256, 4)
__global__ void gemm512(const _Float16* __restrict__ Ah, const _Float16* __restrict__ Wh,
                        const float* __restrict__ bias, const float* __restrict__ w,
                        const _Float16* __restrict__ ah, const float* __restrict__ sumK2,
                        _Float16* out0, _Float16* out1, float* trH0){
  int n0 = blockIdx.x*64, i0 = blockIdx.y*64;
  int t = threadIdx.x;
  int wv = t>>6, l = t&63;
  int r15 = l & 15;
  int krow = (l>>4)*8;
  const _Float16* abase = Ah + (size_t)(n0 + wv*16 + r15)*M_ + krow;
  const _Float16* wb0 = Wh + (size_t)(i0 +  0 + r15)*M_ + krow;
  const _Float16* wb1 = Wh + (size_t)(i0 + 16 + r15)*M_ + krow;
  const _Float16* wb2 = Wh + (size_t)(i0 + 32 + r15)*M_ + krow;
  const _Float16* wb3 = Wh + (size_t)(i0 + 48 + r15)*M_ + krow;
  f32x4 zero = {0.f,0.f,0.f,0.f};
  f32x4 acc[4]; for (int k=0;k<4;++k) acc[k]=zero;
  h8 af_c = *(const h8*)(abase);
  h8 bf_c0 = *(const h8*)(wb0);
  h8 bf_c1 = *(const h8*)(wb1);
  h8 bf_c2 = *(const h8*)(wb2);
  h8 bf_c3 = *(const h8*)(wb3);
  #pragma unroll
  for (int ii = 0; ii < 16; ++ii){
    const int j0 = ii*32;
    h8 af_n, bf_n0, bf_n1, bf_n2, bf_n3;
    if (ii < 15){
      af_n  = *(const h8*)(abase + j0 + 32);
      bf_n0 = *(const h8*)(wb0 + j0 + 32);
      bf_n1 = *(const h8*)(wb1 + j0 + 32);
      bf_n2 = *(const h8*)(wb2 + j0 + 32);
      bf_n3 = *(const h8*)(wb3 + j0 + 32);
    }
    acc[0] = __builtin_amdgcn_mfma_f32_16x16x32_f16(af_c, bf_c0, acc[0], 0, 0, 0);
    acc[1] = __builtin_amdgcn_mfma_f32_16x16x32_f16(af_c, bf_c1, acc[1], 0, 0, 0);
    acc[2] = __builtin_amdgcn_mfma_f32_16x16x32_f16(af_c, bf_c2, acc[2], 0, 0, 0);
    acc[3] = __builtin_amdgcn_mfma_f32_16x16x32_f16(af_c, bf_c3, acc[3], 0, 0, 0);
    if (ii < 15){
      af_c = af_n; bf_c0 = bf_n0; bf_c1 = bf_n1; bf_c2 = bf_n2; bf_c3 = bf_n3;
    }
  }
  if (MODE == 0){
    for (int kt=0;kt<4;++kt) for (int r=0;r<4;++r){
      int n = n0+wv*16+(l>>4)*4+r;
      int i = i0+kt*16+r15;
      float v = acc[kt][r] + bias[i];
      float tl = tanhf(v);
      out0[n*M_+i] = (_Float16)(tl*w[i]);
      out1[n*M_+i] = (_Float16)((1.f-tl*tl)*w[i]);
    }
  } else {
    for (int r=0;r<4;++r){
      int n = n0+wv*16+(l>>4)*4+r;
      float rowpart = 0.f;
      for (int kt=0;kt<4;++kt){
        int i = i0+kt*16+r15;
        float z1 = acc[kt][r] + w[i];
        float a = (float)ah[n*M_+i];
        out0[n*M_+i] = (_Float16)(a*z1);
        rowpart += (1.f-a*a)*z1*sumK2[i];
      }
      for (int m=1;m<16;m<<=1) rowpart += __shfl_xor(rowpart, m);
      if (r15==0) atomicAdd(&trH0[n], rowpart);
    }
  }
}

// ---------------- z0 = az1 @ K0 (N x 80, K=512) ----------------
__launch_bounds__(256, 4)
__global__ void gemmz0(const _Float16* __restrict__ az1h, const _Float16* __restrict__ K0Th,
                       float* z0){
  int n0 = blockIdx.x*64;
  int t = threadIdx.x, wv = t>>6, l = t&63;
  int r15 = l & 15;
  int krow = (l>>4)*8;
  const _Float16* abase = az1h + (size_t)(n0 + wv*16 + r15)*M_ + krow;
  const _Float16* kb0 = K0Th + (size_t)( 0 + r15)*M_ + krow;
  const _Float16* kb1 = K0Th + (size_t)(16 + r15)*M_ + krow;
  const _Float16* kb2 = K0Th + (size_t)(32 + r15)*M_ + krow;
  const _Float16* kb3 = K0Th + (size_t)(48 + r15)*M_ + krow;
  const _Float16* kb4 = K0Th + (size_t)(64 + r15)*M_ + krow;
  f32x4 zero = {0.f,0.f,0.f,0.f};
  f32x4 acc[5]; for (int k=0;k<5;++k) acc[k]=zero;
  h8 af_c = *(const h8*)(abase);
  h8 b0c = *(const h8*)(kb0);
  h8 b1c = *(const h8*)(kb1);
  h8 b2c = *(const h8*)(kb2);
  h8 b3c = *(const h8*)(kb3);
  h8 b4c = *(const h8*)(kb4);
  #pragma unroll
  for (int ii = 0; ii < 16; ++ii){
    const int j0 = ii*32;
    h8 af_n, b0n, b1n, b2n, b3n, b4n;
    if (ii < 15){
      af_n = *(const h8*)(abase + j0 + 32);
      b0n = *(const h8*)(kb0 + j0 + 32);
      b1n = *(const h8*)(kb1 + j0 + 32);
      b2n = *(const h8*)(kb2 + j0 + 32);
      b3n = *(const h8*)(kb3 + j0 + 32);
      b4n = *(const h8*)(kb4 + j0 + 32);
    }
    acc[0] = __builtin_amdgcn_mfma_f32_16x16x32_f16(af_c, b0c, acc[0], 0, 0, 0);
    acc[1] = __builtin_amdgcn_mfma_f32_16x16x32_f16(af_c, b1c, acc[1], 0, 0, 0);
    acc[2] = __builtin_amdgcn_mfma_f32_16x16x32_f16(af_c, b2c, acc[2], 0, 0, 0);
    acc[3] = __builtin_amdgcn_mfma_f32_16x16x32_f16(af_c, b3c, acc[3], 0, 0, 0);
    acc[4] = __builtin_amdgcn_mfma_f32_16x16x32_f16(af_c, b4c, acc[4], 0, 0, 0);
    if (ii < 15){
      af_c = af_n; b0c = b0n; b1c = b1n; b2c = b2n; b3c = b3n; b4c = b4n;
    }
  }
  for (int dt=0; dt<5; ++dt) for (int r=0;r<4;++r){
    int n = n0+wv*16+(l>>4)*4+r;
    int d = dt*16+r15;
    z0[n*80+d] = acc[dt][r];
  }
}

// ---------------- dominant: t1 partials (2-phase gload_lds pipeline) ----------------
// C_n = K1 @ (a_n (.) Kopen).  Block = 256 thr / 4 waves = 64 K1 rows x 2 samples.
// Wave wv owns k-cols [wv*16, wv*16+16): Kopen^T fragment kf[16] lives in 32 VGPRs,
// loaded ONCE (no per-step B staging; per-step B = kf[t]*av[s], 2 packed-f16 muls).
// K1 64x32 j-tile double-buffered in LDS (2x4KB) via global_load_lds width=16 —
// the prefetch lives in the vmem queue + LDS, so the compiler cannot sink it
// (R5/R6 lesson: register-level prefetch gets canonicalized away).
__launch_bounds__(256, 4)
__global__ void kjk7(const _Float16* __restrict__ K1h, const _Float16* __restrict__ K0Th,
                     const _Float16* __restrict__ ah, const _Float16* __restrict__ ch,
                     float* trH0){
  __shared__ _Float16 kbuf[2][64*32];   // [buf][row*32 + j], 4 KB each
  int t = threadIdx.x;
  int n0 = blockIdx.x*2;
  int rg = blockIdx.y;                  // 0..7 : 64-row group of K1
  int i0 = rg*64;
  int wv = t>>6, l = t&63;
  int r15 = l & 15, g = l>>4;
  // Kopen^T fragment: wave's 16 k-cols, all 16 j-steps. 32 VGPRs, loaded once.
  h8 kf[16];
  const _Float16* kfp = K0Th + (size_t)(wv*16 + r15)*M_ + g*8;
  #pragma unroll
  for (int tt = 0; tt < 16; ++tt) kf[tt] = *(const h8*)(kfp + tt*32);
  // a-row pointers (L1 broadcast reads)
  const _Float16* avp0 = ah + (size_t)(n0+0)*M_ + g*8;
  const _Float16* avp1 = ah + (size_t)(n0+1)*M_ + g*8;
  h8 av_c0 = *(const h8*)(avp0);
  h8 av_c1 = *(const h8*)(avp1);
  // K1 tile stage: wave wv stages rows [wv*16, wv*16+16); lane l -> row l>>2, chunk l&3
  const _Float16* gK1 = K1h + (size_t)(i0 + wv*16 + (l>>2))*M_ + (l&3)*8;
  _Float16* lbase = &kbuf[0][0] + wv*512;   // 16 rows * 32 els; HW adds lane*16B
  // prologue: stage step 0 into buf 0
  __builtin_amdgcn_global_load_lds(
      (const __attribute__((address_space(1))) void*)(gK1),
      (__attribute__((address_space(3))) void*)(lbase), 16, 0, 0);
  __syncthreads();
  f32x4 zero = {0.f,0.f,0.f,0.f};
  f32x4 acc[4][2];
  #pragma unroll
  for (int it=0;it<4;++it) for (int s=0;s<2;++s) acc[it][s]=zero;
  #pragma unroll
  for (int step = 0; step < 16; ++step){
    const int cur = step & 1;
    // issue next tile's stage (completes by the NEXT barrier, not this one)
    if (step < 15){
      __builtin_amdgcn_global_load_lds(
          (const __attribute__((address_space(1))) void*)(gK1 + (step+1)*32),
          (__attribute__((address_space(3))) void*)(&kbuf[cur^1][0] + wv*512), 16, 0, 0);
    }
    // prefetch next step's a-fragments
    h8 av_n0, av_n1;
    if (step < 15){
      av_n0 = *(const h8*)(avp0 + (step+1)*32);
      av_n1 = *(const h8*)(avp1 + (step+1)*32);
    }
    // A-fragments (K1 rows) from current LDS buffer
    h8 af0 = *(const h8*)(&kbuf[cur][( 0 + r15)*32 + g*8]);
    h8 af1 = *(const h8*)(&kbuf[cur][(16 + r15)*32 + g*8]);
    h8 af2 = *(const h8*)(&kbuf[cur][(32 + r15)*32 + g*8]);
    h8 af3 = *(const h8*)(&kbuf[cur][(48 + r15)*32 + g*8]);
    // B-fragments: fold a into Kopen (2 h8 muls)
    h8 bf0 = kf[step]*av_c0;
    h8 bf1 = kf[step]*av_c1;
    acc[0][0] = __builtin_amdgcn_mfma_f32_16x16x32_f16(af0, bf0, acc[0][0], 0, 0, 0);
    acc[1][0] = __builtin_amdgcn_mfma_f32_16x16x32_f16(af1, bf0, acc[1][0], 0, 0, 0);
    acc[2][0] = __builtin_amdgcn_mfma_f32_16x16x32_f16(af2, bf0, acc[2][0], 0, 0, 0);
    acc[3][0] = __builtin_amdgcn_mfma_f32_16x16x32_f16(af3, bf0, acc[3][0], 0, 0, 0);
    acc[0][1] = __builtin_amdgcn_mfma_f32_16x16x32_f16(af0, bf1, acc[0][1], 0, 0, 0);
    acc[1][1] = __builtin_amdgcn_mfma_f32_16x16x32_f16(af1, bf1, acc[1][1], 0, 0, 0);
    acc[2][1] = __builtin_amdgcn_mfma_f32_16x16x32_f16(af2, bf1, acc[2][1], 0, 0, 0);
    acc[3][1] = __builtin_amdgcn_mfma_f32_16x16x32_f16(af3, bf1, acc[3][1], 0, 0, 0);
    __syncthreads();
    if (step < 15){ av_c0 = av_n0; av_c1 = av_n1; }
  }
  // epilogue: c-weighted Frobenius reduce.
  // acc[it][s] lane layout: col(l&15) = k-col (summed over), row = i-tile row g*4+r.
  #pragma unroll
  for (int s = 0; s < 2; ++s){
    float part = 0.f;
    #pragma unroll
    for (int it = 0; it < 4; ++it){
      #pragma unroll
      for (int r = 0; r < 4; ++r){
        int i = i0 + it*16 + g*4 + r;
        float ci = (float)ch[(size_t)(n0+s)*M_ + i];
        float v = acc[it][s][r];
        part += ci*v*v;
      }
    }
    for (int m=32;m>=1;m>>=1) part += __shfl_xor(part, m);
    if (l == 0) atomicAdd(&trH0[n0+s], part);
  }
}

// ---------------- final: grad, outputs ----------------
__global__ void finalk(const float* __restrict__ x, const float* __restrict__ tptr,
                       const float* __restrict__ symA, const float* __restrict__ c_w,
                       const float* __restrict__ z0, const float* __restrict__ trH0,
                       float* out){
  __shared__ float sA[DP1*DP1];
  int t = threadIdx.x;
  for (int i = t; i < DP1*DP1; i += 256) sA[i] = symA[i];
  __syncthreads();
  int wv = t>>6, l = t&63;
  int n = blockIdx.x*4 + wv;
  float tval = tptr[0];
  float sv = x[n*64 + l];
  float acc = z0[n*80 + l] + c_w[l];
  for (int e = 0; e < 64; ++e){
    float se = __shfl(sv, e);
    acc += se * sA[l*DP1 + e];     // symA symmetric
  }
  acc += tval * sA[l*DP1 + 64];
  // grad[64]
  float g64 = sv * sA[64*DP1 + l];
  for (int m=32;m>=1;m>>=1) g64 += __shfl_xor(g64, m);
  g64 += tval*sA[64*DP1+64] + z0[n*80+64] + c_w[64];
  float dz = -acc;
  out[n*64 + l] = dz;
  float q = dz*dz;
  for (int m=32;m>=1;m>>=1) q += __shfl_xor(q, m);
  float costL = 0.5f*q;
  if (l == 0){
    out[N_*64 + n]        = -trH0[n];
    out[N_*64 + N_ + n]   = costL;
    out[N_*64 + 2*N_ + n] = fabsf(-g64 + costL);
  }
}

extern "C" void kernel_launch(void* const* d_in, const int* in_sizes, int n_in,
                              void* d_out, int out_size, void* d_ws, size_t ws_size,
                              hipStream_t stream){
  const float* x   = (const float*)d_in[0];
  const float* tp  = (const float*)d_in[1];
  const float* K0  = (const float*)d_in[2];
  const float* b0  = (const float*)d_in[3];
  const float* K1  = (const float*)d_in[4];
  const float* b1  = (const float*)d_in[5];
  const float* w   = (const float*)d_in[6];
  const float* A   = (const float*)d_in[7];
  const float* c_w = (const float*)d_in[8];
  float* out = (float*)d_out;

  char* ws = (char*)d_ws;
  size_t off = 0;
  auto alloc = [&](size_t bytes)->void*{
    void* p = ws + off; off += bytes; off = (off + 255) & ~(size_t)255; return p;
  };
  _Float16* K1h   = (_Float16*)alloc(512*512*2);
  _Float16* K1Th  = (_Float16*)alloc(512*512*2);
  _Float16* K0Th  = (_Float16*)alloc(80*512*2);
  float* symA     = (float*)alloc(DP1*DP1*4);
  float* sumK2    = (float*)alloc(512*4);
  float* params   = (float*)alloc(256);
  _Float16* u0h   = (_Float16*)alloc((size_t)N_*M_*2);
  _Float16* ah    = (_Float16*)alloc((size_t)N_*M_*2);
  _Float16* tl1wh = (_Float16*)alloc((size_t)N_*M_*2);
  _Float16* ch    = (_Float16*)alloc((size_t)N_*M_*2);
  _Float16* az1h  = (_Float16*)alloc((size_t)N_*M_*2);
  float* z0       = (float*)alloc((size_t)N_*80*4);
  float* trH0     = (float*)alloc(N_*4);

  prep1<<<1, 256, 0, stream>>>(A, K0, symA, sumK2, params);
  prep2<<<dim3(8,8), 256, 0, stream>>>(K1, K1h, K1Th);
  prep3<<<160, 256, 0, stream>>>(K0, K0Th);
  openk<<<dim3(N_/64, M_/64), 256, 0, stream>>>(x, tp, K0, b0, u0h, ah, trH0, params);
  gemm512<0><<<dim3(N_/64, M_/64), 256, 0, stream>>>(u0h, K1h, b1, w, nullptr, nullptr,
                                                     tl1wh, ch, nullptr);
  gemm512<1><<<dim3(N_/64, M_/64), 256, 0, stream>>>(tl1wh, K1Th, nullptr, w, ah, sumK2,
                                                     az1h, nullptr, trH0);
  gemmz0<<<N_/64, 256, 0, stream>>>(az1h, K0Th, z0);
  kjk7<<<dim3(N_/2, 8), 256, 0, stream>>>(K1h, K0Th, ah, ch, trH0);
  finalk<<<N_/4, 256, 0, stream>>>(x, tp, symA, c_w, z0, trH0, out);
}

// Round 8
// 263.119 us; speedup vs baseline: 1.4755x; 1.3671x over previous
//
#include <hip/hip_runtime.h>
#include <stdint.h>

#define D_  64
#define DP1 65
#define M_  512
#define N_  4096

typedef float f32x4 __attribute__((ext_vector_type(4)));
typedef _Float16 h8 __attribute__((ext_vector_type(8)));

// ---------------- prep kernels ----------------
__global__ void prep1(const float* __restrict__ A, const float* __restrict__ K0,
                      float* symA, float* sumK2, float* params){
  int t = threadIdx.x;
  for (int idx = t; idx < DP1*DP1; idx += 256){
    int e = idx / DP1, d = idx % DP1;
    float s = 0.f;
    for (int r = 0; r < 10; ++r) s += A[r*DP1+e]*A[r*DP1+d];
    symA[idx] = s;
  }
  for (int m = t; m < M_; m += 256){
    float s = 0.f;
    for (int k = 0; k < D_; ++k){ float v = K0[m*DP1+k]; s += v*v; }
    sumK2[m] = s;
  }
  __syncthreads();
  if (t == 0){
    float tr = 0.f;
    for (int d = 0; d < D_; ++d) tr += symA[d*DP1+d];
    params[0] = tr;
  }
}

// K1 -> f16 row-major + f16 transposed (LDS tile transpose)
__global__ void prep2(const float* __restrict__ K1, _Float16* K1h, _Float16* K1Th){
  __shared__ float tile[64][65];
  int r0 = blockIdx.x*64, c0 = blockIdx.y*64;
  int t = threadIdx.x;
  for (int it = 0; it < 16; ++it){
    int lin = it*256 + t;
    int r = lin >> 6, c = lin & 63;
    float v = K1[(r0+r)*M_ + c0+c];
    tile[r][c] = v;
    K1h[(r0+r)*M_ + c0+c] = (_Float16)v;
  }
  __syncthreads();
  for (int it = 0; it < 16; ++it){
    int lin = it*256 + t;
    int r = lin >> 6, c = lin & 63;
    K1Th[(c0+r)*M_ + (r0+c)] = (_Float16)tile[c][r];
  }
}

// K0T f16, 80 rows x 512 (rows 65..79 zero). Rows 0..63 double as Kopen^T.
__global__ void prep3(const float* __restrict__ K0, _Float16* K0Th){
  int idx = blockIdx.x*256 + threadIdx.x;
  if (idx >= 80*M_) return;
  int d = idx / M_, i = idx % M_;
  float v = (d < DP1) ? K0[i*DP1 + d] : 0.f;
  K0Th[idx] = (_Float16)v;
}

// ---------------- opening + elementwise ----------------
__global__ void openk(const float* __restrict__ x, const float* __restrict__ tptr,
                      const float* __restrict__ K0, const float* __restrict__ b0,
                      _Float16* u0h, _Float16* ah,
                      float* trH0, const float* __restrict__ params){
  __shared__ float sS[64][66];
  __shared__ float sK[64][66];
  int n0 = blockIdx.x*64, m0 = blockIdx.y*64;
  int t = threadIdx.x;
  float tval = tptr[0];
  for (int it = 0; it < 17; ++it){
    int lin = it*256 + t;
    if (lin < 64*65){
      int r = lin/65, c = lin%65;
      sS[r][c] = (c < 64) ? x[(n0+r)*64 + c] : tval;
      sK[r][c] = K0[(m0+r)*DP1 + c];
    }
  }
  __syncthreads();
  int tn = (t>>4)*4, tm = (t&15)*4;
  float acc[4][4] = {};
  for (int e = 0; e < DP1; ++e){
    float sv[4], kv[4];
    for (int i=0;i<4;++i){ sv[i]=sS[tn+i][e]; kv[i]=sK[tm+i][e]; }
    for (int i=0;i<4;++i) for(int j=0;j<4;++j) acc[i][j] += sv[i]*kv[j];
  }
  for (int i=0;i<4;++i) for(int j=0;j<4;++j){
    int n = n0+tn+i, m = m0+tm+j;
    float o = acc[i][j] + b0[m];
    float a = tanhf(o);
    float ax = fabsf(o);
    float u0 = ax + log1pf(expf(-2.f*ax));
    u0h[n*M_+m] = (_Float16)u0;
    ah[n*M_+m]  = (_Float16)a;
  }
  if (m0 == 0 && t < 64) trH0[n0+t] = params[0];
}

// ---------------- 4096x512x512 GEMMs (MODE 0: lin1, MODE 1: z1) ----------------
template<int MODE>
__launch_bounds__(256, 4)
__global__ void gemm512(const _Float16* __restrict__ Ah, const _Float16* __restrict__ Wh,
                        const float* __restrict__ bias, const float* __restrict__ w,
                        const _Float16* __restrict__ ah, const float* __restrict__ sumK2,
                        _Float16* out0, _Float16* out1, float* trH0){
  int n0 = blockIdx.x*64, i0 = blockIdx.y*64;
  int t = threadIdx.x;
  int wv = t>>6, l = t&63;
  int r15 = l & 15;
  int krow = (l>>4)*8;
  const _Float16* abase = Ah + (size_t)(n0 + wv*16 + r15)*M_ + krow;
  const _Float16* wb0 = Wh + (size_t)(i0 +  0 + r15)*M_ + krow;
  const _Float16* wb1 = Wh + (size_t)(i0 + 16 + r15)*M_ + krow;
  const _Float16* wb2 = Wh + (size_t)(i0 + 32 + r15)*M_ + krow;
  const _Float16* wb3 = Wh + (size_t)(i0 + 48 + r15)*M_ + krow;
  f32x4 zero = {0.f,0.f,0.f,0.f};
  f32x4 acc[4]; for (int k=0;k<4;++k) acc[k]=zero;
  h8 af_c = *(const h8*)(abase);
  h8 bf_c0 = *(const h8*)(wb0);
  h8 bf_c1 = *(const h8*)(wb1);
  h8 bf_c2 = *(const h8*)(wb2);
  h8 bf_c3 = *(const h8*)(wb3);
  #pragma unroll
  for (int ii = 0; ii < 16; ++ii){
    const int j0 = ii*32;
    h8 af_n, bf_n0, bf_n1, bf_n2, bf_n3;
    if (ii < 15){
      af_n  = *(const h8*)(abase + j0 + 32);
      bf_n0 = *(const h8*)(wb0 + j0 + 32);
      bf_n1 = *(const h8*)(wb1 + j0 + 32);
      bf_n2 = *(const h8*)(wb2 + j0 + 32);
      bf_n3 = *(const h8*)(wb3 + j0 + 32);
    }
    acc[0] = __builtin_amdgcn_mfma_f32_16x16x32_f16(af_c, bf_c0, acc[0], 0, 0, 0);
    acc[1] = __builtin_amdgcn_mfma_f32_16x16x32_f16(af_c, bf_c1, acc[1], 0, 0, 0);
    acc[2] = __builtin_amdgcn_mfma_f32_16x16x32_f16(af_c, bf_c2, acc[2], 0, 0, 0);
    acc[3] = __builtin_amdgcn_mfma_f32_16x16x32_f16(af_c, bf_c3, acc[3], 0, 0, 0);
    if (ii < 15){
      af_c = af_n; bf_c0 = bf_n0; bf_c1 = bf_n1; bf_c2 = bf_n2; bf_c3 = bf_n3;
    }
  }
  if (MODE == 0){
    for (int kt=0;kt<4;++kt) for (int r=0;r<4;++r){
      int n = n0+wv*16+(l>>4)*4+r;
      int i = i0+kt*16+r15;
      float v = acc[kt][r] + bias[i];
      float tl = tanhf(v);
      out0[n*M_+i] = (_Float16)(tl*w[i]);
      out1[n*M_+i] = (_Float16)((1.f-tl*tl)*w[i]);
    }
  } else {
    for (int r=0;r<4;++r){
      int n = n0+wv*16+(l>>4)*4+r;
      float rowpart = 0.f;
      for (int kt=0;kt<4;++kt){
        int i = i0+kt*16+r15;
        float z1 = acc[kt][r] + w[i];
        float a = (float)ah[n*M_+i];
        out0[n*M_+i] = (_Float16)(a*z1);
        rowpart += (1.f-a*a)*z1*sumK2[i];
      }
      for (int m=1;m<16;m<<=1) rowpart += __shfl_xor(rowpart, m);
      if (r15==0) atomicAdd(&trH0[n], rowpart);
    }
  }
}

// ---------------- z0 = az1 @ K0 (N x 80, K=512) ----------------
__launch_bounds__(256, 4)
__global__ void gemmz0(const _Float16* __restrict__ az1h, const _Float16* __restrict__ K0Th,
                       float* z0){
  int n0 = blockIdx.x*64;
  int t = threadIdx.x, wv = t>>6, l = t&63;
  int r15 = l & 15;
  int krow = (l>>4)*8;
  const _Float16* abase = az1h + (size_t)(n0 + wv*16 + r15)*M_ + krow;
  const _Float16* kb0 = K0Th + (size_t)( 0 + r15)*M_ + krow;
  const _Float16* kb1 = K0Th + (size_t)(16 + r15)*M_ + krow;
  const _Float16* kb2 = K0Th + (size_t)(32 + r15)*M_ + krow;
  const _Float16* kb3 = K0Th + (size_t)(48 + r15)*M_ + krow;
  const _Float16* kb4 = K0Th + (size_t)(64 + r15)*M_ + krow;
  f32x4 zero = {0.f,0.f,0.f,0.f};
  f32x4 acc[5]; for (int k=0;k<5;++k) acc[k]=zero;
  h8 af_c = *(const h8*)(abase);
  h8 b0c = *(const h8*)(kb0);
  h8 b1c = *(const h8*)(kb1);
  h8 b2c = *(const h8*)(kb2);
  h8 b3c = *(const h8*)(kb3);
  h8 b4c = *(const h8*)(kb4);
  #pragma unroll
  for (int ii = 0; ii < 16; ++ii){
    const int j0 = ii*32;
    h8 af_n, b0n, b1n, b2n, b3n, b4n;
    if (ii < 15){
      af_n = *(const h8*)(abase + j0 + 32);
      b0n = *(const h8*)(kb0 + j0 + 32);
      b1n = *(const h8*)(kb1 + j0 + 32);
      b2n = *(const h8*)(kb2 + j0 + 32);
      b3n = *(const h8*)(kb3 + j0 + 32);
      b4n = *(const h8*)(kb4 + j0 + 32);
    }
    acc[0] = __builtin_amdgcn_mfma_f32_16x16x32_f16(af_c, b0c, acc[0], 0, 0, 0);
    acc[1] = __builtin_amdgcn_mfma_f32_16x16x32_f16(af_c, b1c, acc[1], 0, 0, 0);
    acc[2] = __builtin_amdgcn_mfma_f32_16x16x32_f16(af_c, b2c, acc[2], 0, 0, 0);
    acc[3] = __builtin_amdgcn_mfma_f32_16x16x32_f16(af_c, b3c, acc[3], 0, 0, 0);
    acc[4] = __builtin_amdgcn_mfma_f32_16x16x32_f16(af_c, b4c, acc[4], 0, 0, 0);
    if (ii < 15){
      af_c = af_n; b0c = b0n; b1c = b1n; b2c = b2n; b3c = b3n; b4c = b4n;
    }
  }
  for (int dt=0; dt<5; ++dt) for (int r=0;r<4;++r){
    int n = n0+wv*16+(l>>4)*4+r;
    int d = dt*16+r15;
    z0[n*80+d] = acc[dt][r];
  }
}

// ---------------- dominant: t1 partials (register-resident Kopen, barrier-free loop) --
// C_n[k,i] = sum_j Kopen^T[k,j]*a_n[j]*K1[i,j].  Block = 8 samples x 32 K1 rows.
// Wave wv owns k-slice [wv*16,wv*16+16): Kopen^T fragment kf[16 steps] = 64 VGPRs,
// loaded ONCE from global. K1 row-tile (32x512, 32KB) staged ONCE in LDS (XOR-swizzled),
// a-rows (8KB) staged ONCE in LDS. Inner loop: NO barriers, NO global loads —
// 2 swizzled ds_read_b128 (K1) + 8 broadcast LDS reads (a) + 32 pk_mul + 16 MFMA.
// Each K1 fragment feeds 8 MFMAs (8-sample reuse); compiler free to pipeline lgkmcnt.
__launch_bounds__(256, 3)
__global__ void kjk8(const _Float16* __restrict__ K1h, const _Float16* __restrict__ K0Th,
                     const _Float16* __restrict__ ah, const _Float16* __restrict__ ch,
                     float* trH0){
  __shared__ _Float16 sK1[32*512];   // 32 KB, 16B-chunk XOR-swizzled per row
  __shared__ _Float16 sAv[8*512];    // 8 KB
  int t = threadIdx.x;
  int n0 = blockIdx.x*8;             // 8 samples
  int i0 = blockIdx.y*32;            // 32 K1 rows
  int wv = t>>6, l = t&63;
  int c15 = l & 15, g = l>>4;
  // kf: wave's Kopen^T k-slice (k = wv*16 + c15), all 512 j. 64 VGPRs, loaded once.
  h8 kf[16];
  {
    const _Float16* kfp = K0Th + (size_t)(wv*16 + c15)*M_ + g*8;
    #pragma unroll
    for (int tt = 0; tt < 16; ++tt) kf[tt] = *(const h8*)(kfp + tt*32);
  }
  // stage K1 tile (swizzled) and a-rows
  #pragma unroll
  for (int it = 0; it < 8; ++it){
    int cc = it*256 + t;             // 2048 chunks: 32 rows x 64 chunks
    int r = cc >> 6, c = cc & 63;
    h8 v = *(const h8*)(K1h + (size_t)(i0 + r)*M_ + c*8);
    *(h8*)(&sK1[r*512 + ((c ^ (r & 7))*8)]) = v;
  }
  #pragma unroll
  for (int it = 0; it < 2; ++it){
    int cc = it*256 + t;             // 512 chunks: 8 rows x 64 chunks
    int s = cc >> 6, c = cc & 63;
    *(h8*)(&sAv[s*512 + c*8]) = *(const h8*)(ah + (size_t)(n0+s)*M_ + c*8);
  }
  __syncthreads();
  f32x4 zero = {0.f,0.f,0.f,0.f};
  f32x4 acc[2][8];                   // [i-tile][sample]
  #pragma unroll
  for (int tt=0;tt<2;++tt)
    #pragma unroll
    for (int s=0;s<8;++s) acc[tt][s]=zero;
  #pragma unroll
  for (int step = 0; step < 16; ++step){
    // K1 B-fragments (i-cols), swizzled conflict-free reads
    int p0 = (((step*4 + g) ^ (c15 & 7))*8);
    h8 bf0 = *(const h8*)(&sK1[(     c15)*512 + p0]);
    h8 bf1 = *(const h8*)(&sK1[(16 + c15)*512 + p0]);
    // a fragments, broadcast within 16-lane groups
    int aoff = step*32 + g*8;
    h8 av0 = *(const h8*)(&sAv[0*512 + aoff]);
    h8 av1 = *(const h8*)(&sAv[1*512 + aoff]);
    h8 av2 = *(const h8*)(&sAv[2*512 + aoff]);
    h8 av3 = *(const h8*)(&sAv[3*512 + aoff]);
    h8 av4 = *(const h8*)(&sAv[4*512 + aoff]);
    h8 av5 = *(const h8*)(&sAv[5*512 + aoff]);
    h8 av6 = *(const h8*)(&sAv[6*512 + aoff]);
    h8 av7 = *(const h8*)(&sAv[7*512 + aoff]);
    h8 k = kf[step];
    h8 ap;
    ap = k*av0;
    acc[0][0] = __builtin_amdgcn_mfma_f32_16x16x32_f16(ap, bf0, acc[0][0], 0, 0, 0);
    acc[1][0] = __builtin_amdgcn_mfma_f32_16x16x32_f16(ap, bf1, acc[1][0], 0, 0, 0);
    ap = k*av1;
    acc[0][1] = __builtin_amdgcn_mfma_f32_16x16x32_f16(ap, bf0, acc[0][1], 0, 0, 0);
    acc[1][1] = __builtin_amdgcn_mfma_f32_16x16x32_f16(ap, bf1, acc[1][1], 0, 0, 0);
    ap = k*av2;
    acc[0][2] = __builtin_amdgcn_mfma_f32_16x16x32_f16(ap, bf0, acc[0][2], 0, 0, 0);
    acc[1][2] = __builtin_amdgcn_mfma_f32_16x16x32_f16(ap, bf1, acc[1][2], 0, 0, 0);
    ap = k*av3;
    acc[0][3] = __builtin_amdgcn_mfma_f32_16x16x32_f16(ap, bf0, acc[0][3], 0, 0, 0);
    acc[1][3] = __builtin_amdgcn_mfma_f32_16x16x32_f16(ap, bf1, acc[1][3], 0, 0, 0);
    ap = k*av4;
    acc[0][4] = __builtin_amdgcn_mfma_f32_16x16x32_f16(ap, bf0, acc[0][4], 0, 0, 0);
    acc[1][4] = __builtin_amdgcn_mfma_f32_16x16x32_f16(ap, bf1, acc[1][4], 0, 0, 0);
    ap = k*av5;
    acc[0][5] = __builtin_amdgcn_mfma_f32_16x16x32_f16(ap, bf0, acc[0][5], 0, 0, 0);
    acc[1][5] = __builtin_amdgcn_mfma_f32_16x16x32_f16(ap, bf1, acc[1][5], 0, 0, 0);
    ap = k*av6;
    acc[0][6] = __builtin_amdgcn_mfma_f32_16x16x32_f16(ap, bf0, acc[0][6], 0, 0, 0);
    acc[1][6] = __builtin_amdgcn_mfma_f32_16x16x32_f16(ap, bf1, acc[1][6], 0, 0, 0);
    ap = k*av7;
    acc[0][7] = __builtin_amdgcn_mfma_f32_16x16x32_f16(ap, bf0, acc[0][7], 0, 0, 0);
    acc[1][7] = __builtin_amdgcn_mfma_f32_16x16x32_f16(ap, bf1, acc[1][7], 0, 0, 0);
  }
  // epilogue: t1 += c_i * C[k,i]^2 ; D lane layout: col(l&15)=i, row-regs = k (summed)
  #pragma unroll
  for (int s = 0; s < 8; ++s){
    float c0 = (float)ch[(size_t)(n0+s)*M_ + i0 +      c15];
    float c1 = (float)ch[(size_t)(n0+s)*M_ + i0 + 16 + c15];
    f32x4 a0 = acc[0][s], a1 = acc[1][s];
    float part = c0*(a0[0]*a0[0] + a0[1]*a0[1] + a0[2]*a0[2] + a0[3]*a0[3])
               + c1*(a1[0]*a1[0] + a1[1]*a1[1] + a1[2]*a1[2] + a1[3]*a1[3]);
    for (int m=32;m>=1;m>>=1) part += __shfl_xor(part, m);
    if (l == 0) atomicAdd(&trH0[n0+s], part);
  }
}

// ---------------- final: grad, outputs ----------------
__global__ void finalk(const float* __restrict__ x, const float* __restrict__ tptr,
                       const float* __restrict__ symA, const float* __restrict__ c_w,
                       const float* __restrict__ z0, const float* __restrict__ trH0,
                       float* out){
  __shared__ float sA[DP1*DP1];
  int t = threadIdx.x;
  for (int i = t; i < DP1*DP1; i += 256) sA[i] = symA[i];
  __syncthreads();
  int wv = t>>6, l = t&63;
  int n = blockIdx.x*4 + wv;
  float tval = tptr[0];
  float sv = x[n*64 + l];
  float acc = z0[n*80 + l] + c_w[l];
  for (int e = 0; e < 64; ++e){
    float se = __shfl(sv, e);
    acc += se * sA[l*DP1 + e];     // symA symmetric
  }
  acc += tval * sA[l*DP1 + 64];
  // grad[64]
  float g64 = sv * sA[64*DP1 + l];
  for (int m=32;m>=1;m>>=1) g64 += __shfl_xor(g64, m);
  g64 += tval*sA[64*DP1+64] + z0[n*80+64] + c_w[64];
  float dz = -acc;
  out[n*64 + l] = dz;
  float q = dz*dz;
  for (int m=32;m>=1;m>>=1) q += __shfl_xor(q, m);
  float costL = 0.5f*q;
  if (l == 0){
    out[N_*64 + n]        = -trH0[n];
    out[N_*64 + N_ + n]   = costL;
    out[N_*64 + 2*N_ + n] = fabsf(-g64 + costL);
  }
}

extern "C" void kernel_launch(void* const* d_in, const int* in_sizes, int n_in,
                              void* d_out, int out_size, void* d_ws, size_t ws_size,
                              hipStream_t stream){
  const float* x   = (const float*)d_in[0];
  const float* tp  = (const float*)d_in[1];
  const float* K0  = (const float*)d_in[2];
  const float* b0  = (const float*)d_in[3];
  const float* K1  = (const float*)d_in[4];
  const float* b1  = (const float*)d_in[5];
  const float* w   = (const float*)d_in[6];
  const float* A   = (const float*)d_in[7];
  const float* c_w = (const float*)d_in[8];
  float* out = (float*)d_out;

  char* ws = (char*)d_ws;
  size_t off = 0;
  auto alloc = [&](size_t bytes)->void*{
    void* p = ws + off; off += bytes; off = (off + 255) & ~(size_t)255; return p;
  };
  _Float16* K1h   = (_Float16*)alloc(512*512*2);
  _Float16* K1Th  = (_Float16*)alloc(512*512*2);
  _Float16* K0Th  = (_Float16*)alloc(80*512*2);
  float* symA     = (float*)alloc(DP1*DP1*4);
  float* sumK2    = (float*)alloc(512*4);
  float* params   = (float*)alloc(256);
  _Float16* u0h   = (_Float16*)alloc((size_t)N_*M_*2);
  _Float16* ah    = (_Float16*)alloc((size_t)N_*M_*2);
  _Float16* tl1wh = (_Float16*)alloc((size_t)N_*M_*2);
  _Float16* ch    = (_Float16*)alloc((size_t)N_*M_*2);
  _Float16* az1h  = (_Float16*)alloc((size_t)N_*M_*2);
  float* z0       = (float*)alloc((size_t)N_*80*4);
  float* trH0     = (float*)alloc(N_*4);

  prep1<<<1, 256, 0, stream>>>(A, K0, symA, sumK2, params);
  prep2<<<dim3(8,8), 256, 0, stream>>>(K1, K1h, K1Th);
  prep3<<<160, 256, 0, stream>>>(K0, K0Th);
  openk<<<dim3(N_/64, M_/64), 256, 0, stream>>>(x, tp, K0, b0, u0h, ah, trH0, params);
  gemm512<0><<<dim3(N_/64, M_/64), 256, 0, stream>>>(u0h, K1h, b1, w, nullptr, nullptr,
                                                     tl1wh, ch, nullptr);
  gemm512<1><<<dim3(N_/64, M_/64), 256, 0, stream>>>(tl1wh, K1Th, nullptr, w, ah, sumK2,
                                                     az1h, nullptr, trH0);
  gemmz0<<<N_/64, 256, 0, stream>>>(az1h, K0Th, z0);
  kjk8<<<dim3(N_/8, 16), 256, 0, stream>>>(K1h, K0Th, ah, ch, trH0);
  finalk<<<N_/4, 256, 0, stream>>>(x, tp, symA, c_w, z0, trH0, out);
}

// Round 9
// 235.216 us; speedup vs baseline: 1.6505x; 1.1186x over previous
//
#include <hip/hip_runtime.h>
#include <stdint.h>

#define D_  64
#define DP1 65
#define M_  512
#define N_  4096

typedef float f32x4 __attribute__((ext_vector_type(4)));
typedef _Float16 h8 __attribute__((ext_vector_type(8)));

// ---------------- prep kernels ----------------
__global__ void prep1(const float* __restrict__ A, const float* __restrict__ K0,
                      float* symA, float* sumK2, float* params){
  int t = threadIdx.x;
  for (int idx = t; idx < DP1*DP1; idx += 256){
    int e = idx / DP1, d = idx % DP1;
    float s = 0.f;
    for (int r = 0; r < 10; ++r) s += A[r*DP1+e]*A[r*DP1+d];
    symA[idx] = s;
  }
  for (int m = t; m < M_; m += 256){
    float s = 0.f;
    for (int k = 0; k < D_; ++k){ float v = K0[m*DP1+k]; s += v*v; }
    sumK2[m] = s;
  }
  __syncthreads();
  if (t == 0){
    float tr = 0.f;
    for (int d = 0; d < D_; ++d) tr += symA[d*DP1+d];
    params[0] = tr;
  }
}

// K1 -> f16 row-major + f16 transposed (LDS tile transpose)
__global__ void prep2(const float* __restrict__ K1, _Float16* K1h, _Float16* K1Th){
  __shared__ float tile[64][65];
  int r0 = blockIdx.x*64, c0 = blockIdx.y*64;
  int t = threadIdx.x;
  for (int it = 0; it < 16; ++it){
    int lin = it*256 + t;
    int r = lin >> 6, c = lin & 63;
    float v = K1[(r0+r)*M_ + c0+c];
    tile[r][c] = v;
    K1h[(r0+r)*M_ + c0+c] = (_Float16)v;
  }
  __syncthreads();
  for (int it = 0; it < 16; ++it){
    int lin = it*256 + t;
    int r = lin >> 6, c = lin & 63;
    K1Th[(c0+r)*M_ + (r0+c)] = (_Float16)tile[c][r];
  }
}

// K0T f16, 80 rows x 512 (rows 65..79 zero). Rows 0..63 double as Kopen^T.
__global__ void prep3(const float* __restrict__ K0, _Float16* K0Th){
  int idx = blockIdx.x*256 + threadIdx.x;
  if (idx >= 80*M_) return;
  int d = idx / M_, i = idx % M_;
  float v = (d < DP1) ? K0[i*DP1 + d] : 0.f;
  K0Th[idx] = (_Float16)v;
}

// ---------------- opening + elementwise ----------------
__global__ void openk(const float* __restrict__ x, const float* __restrict__ tptr,
                      const float* __restrict__ K0, const float* __restrict__ b0,
                      _Float16* u0h, _Float16* ah,
                      float* trH0, const float* __restrict__ params){
  __shared__ float sS[64][66];
  __shared__ float sK[64][66];
  int n0 = blockIdx.x*64, m0 = blockIdx.y*64;
  int t = threadIdx.x;
  float tval = tptr[0];
  for (int it = 0; it < 17; ++it){
    int lin = it*256 + t;
    if (lin < 64*65){
      int r = lin/65, c = lin%65;
      sS[r][c] = (c < 64) ? x[(n0+r)*64 + c] : tval;
      sK[r][c] = K0[(m0+r)*DP1 + c];
    }
  }
  __syncthreads();
  int tn = (t>>4)*4, tm = (t&15)*4;
  float acc[4][4] = {};
  for (int e = 0; e < DP1; ++e){
    float sv[4], kv[4];
    for (int i=0;i<4;++i){ sv[i]=sS[tn+i][e]; kv[i]=sK[tm+i][e]; }
    for (int i=0;i<4;++i) for(int j=0;j<4;++j) acc[i][j] += sv[i]*kv[j];
  }
  for (int i=0;i<4;++i) for(int j=0;j<4;++j){
    int n = n0+tn+i, m = m0+tm+j;
    float o = acc[i][j] + b0[m];
    float a = tanhf(o);
    float ax = fabsf(o);
    float u0 = ax + log1pf(expf(-2.f*ax));
    u0h[n*M_+m] = (_Float16)u0;
    ah[n*M_+m]  = (_Float16)a;
  }
  if (m0 == 0 && t < 64) trH0[n0+t] = params[0];
}

// ---------------- 4096x512x512 GEMMs (MODE 0: lin1, MODE 1: z1) ----------------
template<int MODE>
__launch_bounds__(256, 4)
__global__ void gemm512(const _Float16* __restrict__ Ah, const _Float16* __restrict__ Wh,
                        const float* __restrict__ bias, const float* __restrict__ w,
                        const _Float16* __restrict__ ah, const float* __restrict__ sumK2,
                        _Float16* out0, _Float16* out1, float* trH0){
  int n0 = blockIdx.x*64, i0 = blockIdx.y*64;
  int t = threadIdx.x;
  int wv = t>>6, l = t&63;
  int r15 = l & 15;
  int krow = (l>>4)*8;
  const _Float16* abase = Ah + (size_t)(n0 + wv*16 + r15)*M_ + krow;
  const _Float16* wb0 = Wh + (size_t)(i0 +  0 + r15)*M_ + krow;
  const _Float16* wb1 = Wh + (size_t)(i0 + 16 + r15)*M_ + krow;
  const _Float16* wb2 = Wh + (size_t)(i0 + 32 + r15)*M_ + krow;
  const _Float16* wb3 = Wh + (size_t)(i0 + 48 + r15)*M_ + krow;
  f32x4 zero = {0.f,0.f,0.f,0.f};
  f32x4 acc[4]; for (int k=0;k<4;++k) acc[k]=zero;
  h8 af_c = *(const h8*)(abase);
  h8 bf_c0 = *(const h8*)(wb0);
  h8 bf_c1 = *(const h8*)(wb1);
  h8 bf_c2 = *(const h8*)(wb2);
  h8 bf_c3 = *(const h8*)(wb3);
  #pragma unroll
  for (int ii = 0; ii < 16; ++ii){
    const int j0 = ii*32;
    h8 af_n, bf_n0, bf_n1, bf_n2, bf_n3;
    if (ii < 15){
      af_n  = *(const h8*)(abase + j0 + 32);
      bf_n0 = *(const h8*)(wb0 + j0 + 32);
      bf_n1 = *(const h8*)(wb1 + j0 + 32);
      bf_n2 = *(const h8*)(wb2 + j0 + 32);
      bf_n3 = *(const h8*)(wb3 + j0 + 32);
    }
    acc[0] = __builtin_amdgcn_mfma_f32_16x16x32_f16(af_c, bf_c0, acc[0], 0, 0, 0);
    acc[1] = __builtin_amdgcn_mfma_f32_16x16x32_f16(af_c, bf_c1, acc[1], 0, 0, 0);
    acc[2] = __builtin_amdgcn_mfma_f32_16x16x32_f16(af_c, bf_c2, acc[2], 0, 0, 0);
    acc[3] = __builtin_amdgcn_mfma_f32_16x16x32_f16(af_c, bf_c3, acc[3], 0, 0, 0);
    if (ii < 15){
      af_c = af_n; bf_c0 = bf_n0; bf_c1 = bf_n1; bf_c2 = bf_n2; bf_c3 = bf_n3;
    }
  }
  if (MODE == 0){
    for (int kt=0;kt<4;++kt) for (int r=0;r<4;++r){
      int n = n0+wv*16+(l>>4)*4+r;
      int i = i0+kt*16+r15;
      float v = acc[kt][r] + bias[i];
      float tl = tanhf(v);
      out0[n*M_+i] = (_Float16)(tl*w[i]);
      out1[n*M_+i] = (_Float16)((1.f-tl*tl)*w[i]);
    }
  } else {
    for (int r=0;r<4;++r){
      int n = n0+wv*16+(l>>4)*4+r;
      float rowpart = 0.f;
      for (int kt=0;kt<4;++kt){
        int i = i0+kt*16+r15;
        float z1 = acc[kt][r] + w[i];
        float a = (float)ah[n*M_+i];
        out0[n*M_+i] = (_Float16)(a*z1);
        rowpart += (1.f-a*a)*z1*sumK2[i];
      }
      for (int m=1;m<16;m<<=1) rowpart += __shfl_xor(rowpart, m);
      if (r15==0) atomicAdd(&trH0[n], rowpart);
    }
  }
}

// ---------------- z0 = az1 @ K0 (N x 80, K=512) ----------------
__launch_bounds__(256, 4)
__global__ void gemmz0(const _Float16* __restrict__ az1h, const _Float16* __restrict__ K0Th,
                       float* z0){
  int n0 = blockIdx.x*64;
  int t = threadIdx.x, wv = t>>6, l = t&63;
  int r15 = l & 15;
  int krow = (l>>4)*8;
  const _Float16* abase = az1h + (size_t)(n0 + wv*16 + r15)*M_ + krow;
  const _Float16* kb0 = K0Th + (size_t)( 0 + r15)*M_ + krow;
  const _Float16* kb1 = K0Th + (size_t)(16 + r15)*M_ + krow;
  const _Float16* kb2 = K0Th + (size_t)(32 + r15)*M_ + krow;
  const _Float16* kb3 = K0Th + (size_t)(48 + r15)*M_ + krow;
  const _Float16* kb4 = K0Th + (size_t)(64 + r15)*M_ + krow;
  f32x4 zero = {0.f,0.f,0.f,0.f};
  f32x4 acc[5]; for (int k=0;k<5;++k) acc[k]=zero;
  h8 af_c = *(const h8*)(abase);
  h8 b0c = *(const h8*)(kb0);
  h8 b1c = *(const h8*)(kb1);
  h8 b2c = *(const h8*)(kb2);
  h8 b3c = *(const h8*)(kb3);
  h8 b4c = *(const h8*)(kb4);
  #pragma unroll
  for (int ii = 0; ii < 16; ++ii){
    const int j0 = ii*32;
    h8 af_n, b0n, b1n, b2n, b3n, b4n;
    if (ii < 15){
      af_n = *(const h8*)(abase + j0 + 32);
      b0n = *(const h8*)(kb0 + j0 + 32);
      b1n = *(const h8*)(kb1 + j0 + 32);
      b2n = *(const h8*)(kb2 + j0 + 32);
      b3n = *(const h8*)(kb3 + j0 + 32);
      b4n = *(const h8*)(kb4 + j0 + 32);
    }
    acc[0] = __builtin_amdgcn_mfma_f32_16x16x32_f16(af_c, b0c, acc[0], 0, 0, 0);
    acc[1] = __builtin_amdgcn_mfma_f32_16x16x32_f16(af_c, b1c, acc[1], 0, 0, 0);
    acc[2] = __builtin_amdgcn_mfma_f32_16x16x32_f16(af_c, b2c, acc[2], 0, 0, 0);
    acc[3] = __builtin_amdgcn_mfma_f32_16x16x32_f16(af_c, b3c, acc[3], 0, 0, 0);
    acc[4] = __builtin_amdgcn_mfma_f32_16x16x32_f16(af_c, b4c, acc[4], 0, 0, 0);
    if (ii < 15){
      af_c = af_n; b0c = b0n; b1c = b1n; b2c = b2n; b3c = b3n; b4c = b4n;
    }
  }
  for (int dt=0; dt<5; ++dt) for (int r=0;r<4;++r){
    int n = n0+wv*16+(l>>4)*4+r;
    int d = dt*16+r15;
    z0[n*80+d] = acc[dt][r];
  }
}

// ---------------- dominant: t1 partials (reg-resident Kopen, barrier-free, T=4) ------
// C_n[k,i] = sum_j Kopen^T[k,j]*a_n[j]*K1[i,j].  Block = 8 samples x 64 K1 rows.
// Wave wv owns k-slice [wv*16,wv*16+16): kf[16] = 64 VGPRs, loaded once.
// K1 row-tile (64x512, 64KB) + a-rows (8KB) staged ONCE; inner loop barrier-free:
// 4 swizzled ds_read_b128 (K1) + 8 broadcast reads (a) + 32 pk_mul + 32 MFMA.
// Each A-fragment (4 pk_mul) now feeds 4 MFMAs (T=4, was 2) -> MFMA-dominant.
__launch_bounds__(256, 2)
__global__ void kjk9(const _Float16* __restrict__ K1h, const _Float16* __restrict__ K0Th,
                     const _Float16* __restrict__ ah, const _Float16* __restrict__ ch,
                     float* trH0){
  __shared__ _Float16 sK1[64*512];   // 64 KB, 16B-chunk XOR-swizzled per row
  __shared__ _Float16 sAv[8*512];    // 8 KB
  int t = threadIdx.x;
  int n0 = blockIdx.x*8;             // 8 samples
  int i0 = blockIdx.y*64;            // 64 K1 rows
  int wv = t>>6, l = t&63;
  int c15 = l & 15, g = l>>4;
  // kf: wave's Kopen^T k-slice (k = wv*16 + c15), all 512 j. 64 VGPRs, loaded once.
  h8 kf[16];
  {
    const _Float16* kfp = K0Th + (size_t)(wv*16 + c15)*M_ + g*8;
    #pragma unroll
    for (int tt = 0; tt < 16; ++tt) kf[tt] = *(const h8*)(kfp + tt*32);
  }
  // stage K1 tile (swizzled) and a-rows
  #pragma unroll
  for (int it = 0; it < 16; ++it){
    int cc = it*256 + t;             // 4096 chunks: 64 rows x 64 chunks
    int r = cc >> 6, c = cc & 63;
    h8 v = *(const h8*)(K1h + (size_t)(i0 + r)*M_ + c*8);
    *(h8*)(&sK1[r*512 + ((c ^ (r & 7))*8)]) = v;
  }
  #pragma unroll
  for (int it = 0; it < 2; ++it){
    int cc = it*256 + t;             // 512 chunks: 8 rows x 64 chunks
    int s = cc >> 6, c = cc & 63;
    *(h8*)(&sAv[s*512 + c*8]) = *(const h8*)(ah + (size_t)(n0+s)*M_ + c*8);
  }
  __syncthreads();
  f32x4 zero = {0.f,0.f,0.f,0.f};
  f32x4 acc[4][8];                   // [i-tile][sample]
  #pragma unroll
  for (int tt=0;tt<4;++tt)
    #pragma unroll
    for (int s=0;s<8;++s) acc[tt][s]=zero;
  #pragma unroll
  for (int step = 0; step < 16; ++step){
    // K1 B-fragments (4 i-tiles), swizzled conflict-free reads
    int p0 = (((step*4 + g) ^ (c15 & 7))*8);
    h8 bf0 = *(const h8*)(&sK1[(     c15)*512 + p0]);
    h8 bf1 = *(const h8*)(&sK1[(16 + c15)*512 + p0]);
    h8 bf2 = *(const h8*)(&sK1[(32 + c15)*512 + p0]);
    h8 bf3 = *(const h8*)(&sK1[(48 + c15)*512 + p0]);
    int aoff = step*32 + g*8;
    h8 k = kf[step];
    #pragma unroll
    for (int s = 0; s < 8; ++s){
      h8 av = *(const h8*)(&sAv[s*512 + aoff]);
      h8 ap = k*av;
      acc[0][s] = __builtin_amdgcn_mfma_f32_16x16x32_f16(ap, bf0, acc[0][s], 0, 0, 0);
      acc[1][s] = __builtin_amdgcn_mfma_f32_16x16x32_f16(ap, bf1, acc[1][s], 0, 0, 0);
      acc[2][s] = __builtin_amdgcn_mfma_f32_16x16x32_f16(ap, bf2, acc[2][s], 0, 0, 0);
      acc[3][s] = __builtin_amdgcn_mfma_f32_16x16x32_f16(ap, bf3, acc[3][s], 0, 0, 0);
    }
  }
  // epilogue: t1 += c_i * C[k,i]^2 ; D lane layout: col(l&15)=i, row-regs = k (summed)
  #pragma unroll
  for (int s = 0; s < 8; ++s){
    float part = 0.f;
    #pragma unroll
    for (int tt = 0; tt < 4; ++tt){
      float ci = (float)ch[(size_t)(n0+s)*M_ + i0 + tt*16 + c15];
      f32x4 a = acc[tt][s];
      part += ci*(a[0]*a[0] + a[1]*a[1] + a[2]*a[2] + a[3]*a[3]);
    }
    for (int m=32;m>=1;m>>=1) part += __shfl_xor(part, m);
    if (l == 0) atomicAdd(&trH0[n0+s], part);
  }
}

// ---------------- final: grad, outputs ----------------
__global__ void finalk(const float* __restrict__ x, const float* __restrict__ tptr,
                       const float* __restrict__ symA, const float* __restrict__ c_w,
                       const float* __restrict__ z0, const float* __restrict__ trH0,
                       float* out){
  __shared__ float sA[DP1*DP1];
  int t = threadIdx.x;
  for (int i = t; i < DP1*DP1; i += 256) sA[i] = symA[i];
  __syncthreads();
  int wv = t>>6, l = t&63;
  int n = blockIdx.x*4 + wv;
  float tval = tptr[0];
  float sv = x[n*64 + l];
  float acc = z0[n*80 + l] + c_w[l];
  for (int e = 0; e < 64; ++e){
    float se = __shfl(sv, e);
    acc += se * sA[l*DP1 + e];     // symA symmetric
  }
  acc += tval * sA[l*DP1 + 64];
  // grad[64]
  float g64 = sv * sA[64*DP1 + l];
  for (int m=32;m>=1;m>>=1) g64 += __shfl_xor(g64, m);
  g64 += tval*sA[64*DP1+64] + z0[n*80+64] + c_w[64];
  float dz = -acc;
  out[n*64 + l] = dz;
  float q = dz*dz;
  for (int m=32;m>=1;m>>=1) q += __shfl_xor(q, m);
  float costL = 0.5f*q;
  if (l == 0){
    out[N_*64 + n]        = -trH0[n];
    out[N_*64 + N_ + n]   = costL;
    out[N_*64 + 2*N_ + n] = fabsf(-g64 + costL);
  }
}

extern "C" void kernel_launch(void* const* d_in, const int* in_sizes, int n_in,
                              void* d_out, int out_size, void* d_ws, size_t ws_size,
                              hipStream_t stream){
  const float* x   = (const float*)d_in[0];
  const float* tp  = (const float*)d_in[1];
  const float* K0  = (const float*)d_in[2];
  const float* b0  = (const float*)d_in[3];
  const float* K1  = (const float*)d_in[4];
  const float* b1  = (const float*)d_in[5];
  const float* w   = (const float*)d_in[6];
  const float* A   = (const float*)d_in[7];
  const float* c_w = (const float*)d_in[8];
  float* out = (float*)d_out;

  char* ws = (char*)d_ws;
  size_t off = 0;
  auto alloc = [&](size_t bytes)->void*{
    void* p = ws + off; off += bytes; off = (off + 255) & ~(size_t)255; return p;
  };
  _Float16* K1h   = (_Float16*)alloc(512*512*2);
  _Float16* K1Th  = (_Float16*)alloc(512*512*2);
  _Float16* K0Th  = (_Float16*)alloc(80*512*2);
  float* symA     = (float*)alloc(DP1*DP1*4);
  float* sumK2    = (float*)alloc(512*4);
  float* params   = (float*)alloc(256);
  _Float16* u0h   = (_Float16*)alloc((size_t)N_*M_*2);
  _Float16* ah    = (_Float16*)alloc((size_t)N_*M_*2);
  _Float16* tl1wh = (_Float16*)alloc((size_t)N_*M_*2);
  _Float16* ch    = (_Float16*)alloc((size_t)N_*M_*2);
  _Float16* az1h  = (_Float16*)alloc((size_t)N_*M_*2);
  float* z0       = (float*)alloc((size_t)N_*80*4);
  float* trH0     = (float*)alloc(N_*4);

  prep1<<<1, 256, 0, stream>>>(A, K0, symA, sumK2, params);
  prep2<<<dim3(8,8), 256, 0, stream>>>(K1, K1h, K1Th);
  prep3<<<160, 256, 0, stream>>>(K0, K0Th);
  openk<<<dim3(N_/64, M_/64), 256, 0, stream>>>(x, tp, K0, b0, u0h, ah, trH0, params);
  gemm512<0><<<dim3(N_/64, M_/64), 256, 0, stream>>>(u0h, K1h, b1, w, nullptr, nullptr,
                                                     tl1wh, ch, nullptr);
  gemm512<1><<<dim3(N_/64, M_/64), 256, 0, stream>>>(tl1wh, K1Th, nullptr, w, ah, sumK2,
                                                     az1h, nullptr, trH0);
  gemmz0<<<N_/64, 256, 0, stream>>>(az1h, K0Th, z0);
  kjk9<<<dim3(N_/8, 8), 256, 0, stream>>>(K1h, K0Th, ah, ch, trH0);
  finalk<<<N_/4, 256, 0, stream>>>(x, tp, symA, c_w, z0, trH0, out);
}